// Round 8
// baseline (403.332 us; speedup 1.0000x reference)
//
#include <hip/hip_runtime.h>
#include <hip/hip_fp16.h>

#define NN 50000   // nodes
#define NE 800000  // edges
#define NH 128     // hidden
#define NG 32      // graphs
#define NL 4       // layers
#define NB 196     // scan blocks = ceil(NN/256)
#define WSLOT (NH * NH)  // 16384 elements per weight slot

typedef __attribute__((ext_vector_type(8))) short bf16x8;
typedef __attribute__((ext_vector_type(4))) float f32x4;
typedef __attribute__((ext_vector_type(2))) float f32x2;

__device__ inline short f2bf(float x) {
  union { float f; unsigned u; } v;
  v.f = x;
  unsigned r = v.u + 0x7FFF + ((v.u >> 16) & 1);
  return (short)(r >> 16);
}
__device__ inline float bf2f(short s) {
  union { unsigned u; float f; } v;
  v.u = ((unsigned)(unsigned short)s) << 16;
  return v.f;
}

// 256-thread block exclusive scan (wave shuffle + 4-wave combine)
__device__ inline int block_exscan(int v) {
  __shared__ int wsum[4];
  int tid = threadIdx.x, wave = tid >> 6, lane = tid & 63;
  int x = v;
#pragma unroll
  for (int off = 1; off < 64; off <<= 1) {
    int y = __shfl_up(x, off, 64);
    if (lane >= off) x += y;
  }
  if (lane == 63) wsum[wave] = x;
  __syncthreads();
  int wp = 0;
  if (wave > 0) wp += wsum[0];
  if (wave > 1) wp += wsum[1];
  if (wave > 2) wp += wsum[2];
  return wp + x - v;
}

// ---------------- split W into bf16 hi/lo, swizzled into MFMA fragment order ----
// frag layout: idx = ((ks*8 + t)*64 + lane)*8 + j  <->  W[n][k],
//   n = t*16 + (lane&15), k = ks*32 + (lane>>4)*8 + j
__global__ __launch_bounds__(256) void prep_swizzle(const float* __restrict__ W_emb,
                                                    const float* __restrict__ W_layers,
                                                    short* __restrict__ hi,
                                                    short* __restrict__ lo) {
  int i = blockIdx.x * 256 + threadIdx.x;
  if (i >= 5 * WSLOT) return;
  int slot = i >> 14, f = i & (WSLOT - 1);
  int j = f & 7, lane = (f >> 3) & 63, tt = (f >> 9) & 7, ks = f >> 12;
  int n = tt * 16 + (lane & 15);
  int k = ks * 32 + ((lane >> 4) & 3) * 8 + j;
  const float* W = slot ? (W_layers + (size_t)(slot - 1) * WSLOT) : W_emb;
  float x = W[n * NH + k];
  short hh = f2bf(x);
  hi[i] = hh;
  lo[i] = f2bf(x - bf2f(hh));
}

// ---------------- degree histogram over targets; atomic return = edge rank ------
__global__ __launch_bounds__(256) void hist_kernel(const int* __restrict__ col,
                                                   int* __restrict__ cnt,
                                                   int* __restrict__ rank) {
  int e = blockIdx.x * 256 + threadIdx.x;
  if (e < NE) rank[e] = atomicAdd(&cnt[col[e]], 1);
}

// ---------------- scan stage 1: per-block sum of cnt, plus dis ----------------
__global__ __launch_bounds__(256) void scan1_kernel(const int* __restrict__ cnt,
                                                    int* __restrict__ bsum,
                                                    float* __restrict__ dis) {
  int i = blockIdx.x * 256 + threadIdx.x;
  int v = (i < NN) ? cnt[i] : 0;
  if (i < NN) dis[i] = rsqrtf((float)(v + 1));
  int lane = threadIdx.x & 63;
  int s = v;
#pragma unroll
  for (int off = 32; off; off >>= 1) s += __shfl_down(s, off, 64);
  __shared__ int ws[4];
  if (lane == 0) ws[threadIdx.x >> 6] = s;
  __syncthreads();
  if (threadIdx.x == 0) bsum[blockIdx.x] = ws[0] + ws[1] + ws[2] + ws[3];
}

// ---------------- scan stage 2: exclusive scan of NB block sums ----------------
__global__ __launch_bounds__(256) void scan2_kernel(const int* __restrict__ bsum,
                                                    int* __restrict__ ebsum) {
  int tid = threadIdx.x;
  int v = (tid < NB) ? bsum[tid] : 0;
  int ex = block_exscan(v);
  if (tid < NB) ebsum[tid] = ex;
}

// ---------------- scan stage 3: block-local scan + block offset ----------------
__global__ __launch_bounds__(256) void scan3_kernel(const int* __restrict__ cnt,
                                                    const int* __restrict__ ebsum,
                                                    int* __restrict__ offs) {
  int i = blockIdx.x * 256 + threadIdx.x;
  int v = (i < NN) ? cnt[i] : 0;
  int ex = block_exscan(v);
  if (i < NN) offs[i] = ebsum[blockIdx.x] + ex;
}

// ---------------- CSR fill (no atomics: rank precomputed by hist) ----------------
__global__ __launch_bounds__(256) void fill_kernel(const int* __restrict__ row,
                                                   const int* __restrict__ col,
                                                   const int* __restrict__ rank,
                                                   const float* __restrict__ dis,
                                                   const int* __restrict__ offs,
                                                   int2* __restrict__ csr) {
  int e = blockIdx.x * 256 + threadIdx.x;
  if (e < NE) {
    int d = col[e];
    int s = row[e];
    int pos = offs[d] + rank[e];
    csr[pos] = make_int2(s, __float_as_int(dis[s] * dis[d]));
  }
}

// ---------------- split-bf16 MFMA GEMM: Y[N,128] = X[N,128] @ W[128,128]^T ------
// W (hi+lo, fragment-linear) staged in LDS once per block: B-frag reads become
// conflict-free ds_read_b128 instead of per-wave L2 round-trips.
// 512 threads = 8 waves x 16 rows = 128 rows/block. LDS 64KB -> 2 blocks/CU.
// FP8_OUT=false: D[m <- A-op(X)][n <- B-op(W)], fp32 stores (+bias).
// FP8_OUT=true : operands swapped so each lane holds 4 consecutive channels
//                of one node -> packed fp8 dword stores.
template <bool FP8_OUT>
__global__ __launch_bounds__(512) void gemm_mfma(const float* __restrict__ X,
                                                 const short* __restrict__ Whi,
                                                 const short* __restrict__ Wlo,
                                                 const float* __restrict__ bias,
                                                 float* __restrict__ Yf,
                                                 unsigned char* __restrict__ Y8) {
  __shared__ short Wh[WSLOT];  // 32 KB
  __shared__ short Wl[WSLOT];  // 32 KB
  int tid = threadIdx.x;
#pragma unroll
  for (int i = tid * 8; i < WSLOT; i += 512 * 8) {
    *(bf16x8*)&Wh[i] = *(const bf16x8*)(Whi + i);
    *(bf16x8*)&Wl[i] = *(const bf16x8*)(Wlo + i);
  }
  __syncthreads();

  int wave = tid >> 6, lane = tid & 63;
  int quad = lane >> 4, r16 = lane & 15;
  int m0 = blockIdx.x * 128 + wave * 16;
  if (m0 >= NN) return;  // NN % 16 == 0
  int mA = m0 + r16;

  f32x4 acc[8];
#pragma unroll
  for (int t = 0; t < 8; ++t) acc[t] = (f32x4){0.f, 0.f, 0.f, 0.f};

#pragma unroll
  for (int ks = 0; ks < 4; ++ks) {
    int klane = ks * 32 + quad * 8;
    const float* xr = X + (size_t)mA * NH + klane;
    float4 a0 = *(const float4*)xr;
    float4 a1 = *(const float4*)(xr + 4);
    float af[8] = {a0.x, a0.y, a0.z, a0.w, a1.x, a1.y, a1.z, a1.w};
    bf16x8 xhi, xlo;
#pragma unroll
    for (int j = 0; j < 8; ++j) {
      short h = f2bf(af[j]);
      xhi[j] = h;
      xlo[j] = f2bf(af[j] - bf2f(h));
    }
#pragma unroll
    for (int t = 0; t < 8; ++t) {
      int fidx = ((ks * 8 + t) * 64 + lane) << 3;
      bf16x8 whi = *(const bf16x8*)&Wh[fidx];
      bf16x8 wlo = *(const bf16x8*)&Wl[fidx];
      if (FP8_OUT) {  // A-op = W, B-op = X
        acc[t] = __builtin_amdgcn_mfma_f32_16x16x32_bf16(whi, xhi, acc[t], 0, 0, 0);
        acc[t] = __builtin_amdgcn_mfma_f32_16x16x32_bf16(whi, xlo, acc[t], 0, 0, 0);
        acc[t] = __builtin_amdgcn_mfma_f32_16x16x32_bf16(wlo, xhi, acc[t], 0, 0, 0);
      } else {        // A-op = X, B-op = W
        acc[t] = __builtin_amdgcn_mfma_f32_16x16x32_bf16(xhi, whi, acc[t], 0, 0, 0);
        acc[t] = __builtin_amdgcn_mfma_f32_16x16x32_bf16(xlo, whi, acc[t], 0, 0, 0);
        acc[t] = __builtin_amdgcn_mfma_f32_16x16x32_bf16(xhi, wlo, acc[t], 0, 0, 0);
      }
    }
  }
  if (FP8_OUT) {
    // lane holds node m0+r16, channels t*16 + quad*4 + r
    unsigned* dst = (unsigned*)(Y8 + (size_t)(m0 + r16) * NH);
#pragma unroll
    for (int t = 0; t < 8; ++t) {
      int v = 0;
      v = __builtin_amdgcn_cvt_pk_fp8_f32(acc[t][0], acc[t][1], v, 0);
      v = __builtin_amdgcn_cvt_pk_fp8_f32(acc[t][2], acc[t][3], v, 1);
      dst[t * 4 + quad] = (unsigned)v;
    }
  } else {
    int mrow = m0 + quad * 4;
#pragma unroll
    for (int t = 0; t < 8; ++t) {
      int col = t * 16 + r16;
      float bb = bias ? bias[col] : 0.f;
#pragma unroll
      for (int r = 0; r < 4; ++r)
        Yf[(size_t)(mrow + r) * NH + col] = acc[t][r] + bb;
    }
  }
}

// ---------------- fused aggregate + bias + relu + residual + layernorm ----------
// one wave per node; t is fp8 e4m3; 4 channels/lane x 32 lanes per edge, 2 edges
// per wave-instruction. Epilogue operands (h row, bias, gamma, beta, Wout) are
// prefetched BEFORE the edge loop so the cold h load overlaps the gathers.
__global__ __launch_bounds__(256) void aggregate_kernel(
    const unsigned char* __restrict__ t8, float* __restrict__ h,
    const float* __restrict__ dis, const int* __restrict__ offs,
    const int* __restrict__ cnt, const int2* __restrict__ csr,
    const float* __restrict__ bias, const float* __restrict__ gamma,
    const float* __restrict__ beta, const float* __restrict__ Wout,
    float* __restrict__ nodeval) {
  int node = blockIdx.x * 4 + (threadIdx.x >> 6);
  int lane = threadIdx.x & 63;
  if (node >= NN) return;
  int hf = lane >> 5;        // which edge of the pair
  int c32 = lane & 31;       // dword index within row (4 fp8 channels)
  int c4 = c32 << 2;         // channel base
  const unsigned* t32 = (const unsigned*)t8;

  // ---- prefetch epilogue operands (overlap with gather loop) ----
  float4 hv = *(const float4*)(h + (size_t)node * NH + c4);
  float4 bv = *(const float4*)(bias + c4);
  float4 gv = *(const float4*)(gamma + c4);
  float4 bt = *(const float4*)(beta + c4);
  float4 wv = make_float4(0.f, 0.f, 0.f, 0.f);
  if (Wout) wv = *(const float4*)(Wout + c4);

  float dii = dis[node];
  float sl = dii * dii;      // self-loop norm
  float4 a = make_float4(0.f, 0.f, 0.f, 0.f);
  if (hf == 0) {  // self loop handled by half 0
    unsigned raw = t32[(size_t)node * 32 + c32];
    f32x2 lo2 = __builtin_amdgcn_cvt_pk_f32_fp8(raw, 0);
    f32x2 hi2 = __builtin_amdgcn_cvt_pk_f32_fp8(raw, 1);
    a.x = lo2.x * sl; a.y = lo2.y * sl; a.z = hi2.x * sl; a.w = hi2.y * sl;
  }
  int s0 = offs[node];
  int e = cnt[node];
  int j = 0;
  for (; j + 16 <= e; j += 16) {  // 8 pairs
    int2 p[8];
    unsigned raw[8];
#pragma unroll
    for (int u = 0; u < 8; ++u) p[u] = csr[s0 + j + 2 * u + hf];
#pragma unroll
    for (int u = 0; u < 8; ++u) raw[u] = t32[(size_t)p[u].x * 32 + c32];
#pragma unroll
    for (int u = 0; u < 8; ++u) {
      float w = __int_as_float(p[u].y);
      f32x2 lo2 = __builtin_amdgcn_cvt_pk_f32_fp8(raw[u], 0);
      f32x2 hi2 = __builtin_amdgcn_cvt_pk_f32_fp8(raw[u], 1);
      a.x += lo2.x * w; a.y += lo2.y * w; a.z += hi2.x * w; a.w += hi2.y * w;
    }
  }
  for (; j + 8 <= e; j += 8) {  // 4 pairs
    int2 p[4];
    unsigned raw[4];
#pragma unroll
    for (int u = 0; u < 4; ++u) p[u] = csr[s0 + j + 2 * u + hf];
#pragma unroll
    for (int u = 0; u < 4; ++u) raw[u] = t32[(size_t)p[u].x * 32 + c32];
#pragma unroll
    for (int u = 0; u < 4; ++u) {
      float w = __int_as_float(p[u].y);
      f32x2 lo2 = __builtin_amdgcn_cvt_pk_f32_fp8(raw[u], 0);
      f32x2 hi2 = __builtin_amdgcn_cvt_pk_f32_fp8(raw[u], 1);
      a.x += lo2.x * w; a.y += lo2.y * w; a.z += hi2.x * w; a.w += hi2.y * w;
    }
  }
  for (; j < e; j += 2) {  // masked tail, 1 pair
    int idx = j + hf;
    int2 p = (idx < e) ? csr[s0 + idx] : make_int2(node, 0);
    float w = __int_as_float(p.y);
    unsigned raw = t32[(size_t)p.x * 32 + c32];
    f32x2 lo2 = __builtin_amdgcn_cvt_pk_f32_fp8(raw, 0);
    f32x2 hi2 = __builtin_amdgcn_cvt_pk_f32_fp8(raw, 1);
    a.x += lo2.x * w; a.y += lo2.y * w; a.z += hi2.x * w; a.w += hi2.y * w;
  }
  // combine the two edge-halves: lanes 0-31 <- + lanes 32-63
  a.x += __shfl_down(a.x, 32, 64);
  a.y += __shfl_down(a.y, 32, 64);
  a.z += __shfl_down(a.z, 32, 64);
  a.w += __shfl_down(a.w, 32, 64);
  // epilogue: lanes 0-31 hold 4 channels each (lanes 32-63 shadow harmlessly)
  float v0 = hv.x + fmaxf(a.x + bv.x, 0.f);
  float v1 = hv.y + fmaxf(a.y + bv.y, 0.f);
  float v2 = hv.z + fmaxf(a.z + bv.z, 0.f);
  float v3 = hv.w + fmaxf(a.w + bv.w, 0.f);
  float s = v0 + v1 + v2 + v3;
  float s2 = v0 * v0 + v1 * v1 + v2 * v2 + v3 * v3;
#pragma unroll
  for (int off = 16; off; off >>= 1) {  // butterfly within 32-lane group
    s += __shfl_xor(s, off, 64);
    s2 += __shfl_xor(s2, off, 64);
  }
  float mean = s * (1.f / 128.f);
  float var = fmaxf(s2 * (1.f / 128.f) - mean * mean, 0.f);
  float inv = rsqrtf(var + 1e-5f);
  float4 o;
  o.x = (v0 - mean) * inv * gv.x + bt.x;
  o.y = (v1 - mean) * inv * gv.y + bt.y;
  o.z = (v2 - mean) * inv * gv.z + bt.z;
  o.w = (v3 - mean) * inv * gv.w + bt.w;
  if (lane < 32) *(float4*)(h + (size_t)node * NH + c4) = o;
  if (Wout) {  // fused readout dot (last layer)
    float d = o.x * wv.x + o.y * wv.y + o.z * wv.z + o.w * wv.w;
#pragma unroll
    for (int off = 16; off; off >>= 1) d += __shfl_xor(d, off, 64);
    if (lane == 0) nodeval[node] = d;
  }
}

// ---------------- stage 2: LDS-binned segment reduction ----------------
__global__ __launch_bounds__(256) void reduce_pool_kernel(
    const float* __restrict__ nodeval, const int* __restrict__ batch,
    float* __restrict__ gsum, int* __restrict__ gcnt) {
  __shared__ float bins[NG];
  __shared__ int cbins[NG];
  int tid = threadIdx.x;
  if (tid < NG) {
    bins[tid] = 0.f;
    cbins[tid] = 0;
  }
  __syncthreads();
  int i = blockIdx.x * 256 + tid;
  if (i < NN) {
    int g = batch[i];
    atomicAdd(&bins[g], nodeval[i]);
    atomicAdd(&cbins[g], 1);
  }
  __syncthreads();
  if (tid < NG) {
    if (cbins[tid]) {
      atomicAdd(&gsum[tid], bins[tid]);
      atomicAdd(&gcnt[tid], cbins[tid]);
    }
  }
}

__global__ void finalize_kernel(const float* __restrict__ gsum,
                                const int* __restrict__ gcnt,
                                float* __restrict__ out) {
  int g = threadIdx.x;
  if (g < NG) out[g] = gsum[g] / fmaxf((float)gcnt[g], 1.0f);
}

extern "C" void kernel_launch(void* const* d_in, const int* in_sizes, int n_in,
                              void* d_out, int out_size, void* d_ws, size_t ws_size,
                              hipStream_t stream) {
  const float* x = (const float*)d_in[0];
  const int* eidx = (const int*)d_in[1];
  const int* batch = (const int*)d_in[2];
  const float* W_emb = (const float*)d_in[3];
  const float* b_emb = (const float*)d_in[4];
  const float* W_layers = (const float*)d_in[5];
  const float* b_layers = (const float*)d_in[6];
  const float* ln_gamma = (const float*)d_in[7];
  const float* ln_beta = (const float*)d_in[8];
  const float* W_out = (const float*)d_in[9];
  float* out = (float*)d_out;

  char* ws = (char*)d_ws;
  unsigned char* t8 = (unsigned char*)ws; ws += (size_t)NN * NH;  // fp8 messages
  float* h = (float*)ws;        ws += (size_t)NN * NH * 4;
  short* Whi = (short*)ws;      ws += (size_t)5 * WSLOT * 2;
  short* Wlo = (short*)ws;      ws += (size_t)5 * WSLOT * 2;
  float* dis = (float*)ws;      ws += (size_t)NN * 4;
  int2* csr = (int2*)ws;        ws += (size_t)NE * 8;
  int* rank = (int*)ws;         ws += (size_t)NE * 4;
  int* offs = (int*)ws;         ws += (size_t)NN * 4;
  float* nodeval = (float*)ws;  ws += (size_t)NN * 4;
  int* bsum = (int*)ws;         ws += (size_t)NB * 4;
  int* ebsum = (int*)ws;        ws += (size_t)NB * 4;
  char* zero_base = ws;
  int* cnt = (int*)ws;          ws += (size_t)NN * 4;
  float* gsum = (float*)ws;     ws += (size_t)NG * 4;
  int* gcnt = (int*)ws;         ws += (size_t)NG * 4;
  size_t zero_bytes = (size_t)(ws - zero_base);
  hipMemsetAsync(zero_base, 0, zero_bytes, stream);

  const int* erow = eidx;        // edge_index[0] = sources
  const int* ecol = eidx + NE;   // edge_index[1] = targets

  prep_swizzle<<<(5 * WSLOT + 255) / 256, 256, 0, stream>>>(W_emb, W_layers, Whi,
                                                            Wlo);
  hist_kernel<<<(NE + 255) / 256, 256, 0, stream>>>(ecol, cnt, rank);
  scan1_kernel<<<NB, 256, 0, stream>>>(cnt, bsum, dis);
  scan2_kernel<<<1, 256, 0, stream>>>(bsum, ebsum);
  scan3_kernel<<<NB, 256, 0, stream>>>(cnt, ebsum, offs);
  fill_kernel<<<(NE + 255) / 256, 256, 0, stream>>>(erow, ecol, rank, dis, offs,
                                                    csr);
  int gblk = (NN + 127) / 128;
  gemm_mfma<false><<<gblk, 512, 0, stream>>>(x, Whi, Wlo, b_emb, h, nullptr);
  for (int l = 0; l < NL; ++l) {
    gemm_mfma<true><<<gblk, 512, 0, stream>>>(
        h, Whi + (size_t)(l + 1) * WSLOT, Wlo + (size_t)(l + 1) * WSLOT,
        nullptr, nullptr, t8);
    bool last = (l == NL - 1);
    aggregate_kernel<<<(NN + 3) / 4, 256, 0, stream>>>(
        t8, h, dis, offs, cnt, csr, b_layers + (size_t)l * NH,
        ln_gamma + (size_t)l * NH, ln_beta + (size_t)l * NH,
        last ? W_out : nullptr, nodeval);
  }
  reduce_pool_kernel<<<(NN + 255) / 256, 256, 0, stream>>>(nodeval, batch, gsum,
                                                           gcnt);
  finalize_kernel<<<1, 64, 0, stream>>>(gsum, gcnt, out);
}

// Round 9
// 377.185 us; speedup vs baseline: 1.0693x; 1.0693x over previous
//
#include <hip/hip_runtime.h>
#include <hip/hip_fp16.h>

#define NN 50000   // nodes
#define NE 800000  // edges
#define NH 128     // hidden
#define NG 32      // graphs
#define NL 4       // layers
#define NB 196     // scan blocks = ceil(NN/256)
#define WSLOT (NH * NH)  // 16384 elements per weight slot

typedef __attribute__((ext_vector_type(8))) short bf16x8;
typedef __attribute__((ext_vector_type(4))) float f32x4;
typedef __attribute__((ext_vector_type(2))) float f32x2;

__device__ inline short f2bf(float x) {
  union { float f; unsigned u; } v;
  v.f = x;
  unsigned r = v.u + 0x7FFF + ((v.u >> 16) & 1);
  return (short)(r >> 16);
}
__device__ inline float bf2f(short s) {
  union { unsigned u; float f; } v;
  v.u = ((unsigned)(unsigned short)s) << 16;
  return v.f;
}

// 256-thread block exclusive scan (wave shuffle + 4-wave combine)
__device__ inline int block_exscan(int v) {
  __shared__ int wsum[4];
  int tid = threadIdx.x, wave = tid >> 6, lane = tid & 63;
  int x = v;
#pragma unroll
  for (int off = 1; off < 64; off <<= 1) {
    int y = __shfl_up(x, off, 64);
    if (lane >= off) x += y;
  }
  if (lane == 63) wsum[wave] = x;
  __syncthreads();
  int wp = 0;
  if (wave > 0) wp += wsum[0];
  if (wave > 1) wp += wsum[1];
  if (wave > 2) wp += wsum[2];
  return wp + x - v;
}

// ---------------- split W into bf16 hi/lo, swizzled into MFMA fragment order ----
// frag layout: idx = ((ks*8 + t)*64 + lane)*8 + j  <->  W[n][k],
//   n = t*16 + (lane&15), k = ks*32 + (lane>>4)*8 + j
__global__ __launch_bounds__(256) void prep_swizzle(const float* __restrict__ W_emb,
                                                    const float* __restrict__ W_layers,
                                                    short* __restrict__ hi,
                                                    short* __restrict__ lo) {
  int i = blockIdx.x * 256 + threadIdx.x;
  if (i >= 5 * WSLOT) return;
  int slot = i >> 14, f = i & (WSLOT - 1);
  int j = f & 7, lane = (f >> 3) & 63, tt = (f >> 9) & 7, ks = f >> 12;
  int n = tt * 16 + (lane & 15);
  int k = ks * 32 + ((lane >> 4) & 3) * 8 + j;
  const float* W = slot ? (W_layers + (size_t)(slot - 1) * WSLOT) : W_emb;
  float x = W[n * NH + k];
  short hh = f2bf(x);
  hi[i] = hh;
  lo[i] = f2bf(x - bf2f(hh));
}

// ---------------- degree histogram over targets; atomic return = edge rank ------
__global__ __launch_bounds__(256) void hist_kernel(const int* __restrict__ col,
                                                   int* __restrict__ cnt,
                                                   int* __restrict__ rank) {
  int e = blockIdx.x * 256 + threadIdx.x;
  if (e < NE) rank[e] = atomicAdd(&cnt[col[e]], 1);
}

// ---------------- scan stage 1: per-block sum of cnt, plus dis ----------------
__global__ __launch_bounds__(256) void scan1_kernel(const int* __restrict__ cnt,
                                                    int* __restrict__ bsum,
                                                    float* __restrict__ dis) {
  int i = blockIdx.x * 256 + threadIdx.x;
  int v = (i < NN) ? cnt[i] : 0;
  if (i < NN) dis[i] = rsqrtf((float)(v + 1));
  int lane = threadIdx.x & 63;
  int s = v;
#pragma unroll
  for (int off = 32; off; off >>= 1) s += __shfl_down(s, off, 64);
  __shared__ int ws[4];
  if (lane == 0) ws[threadIdx.x >> 6] = s;
  __syncthreads();
  if (threadIdx.x == 0) bsum[blockIdx.x] = ws[0] + ws[1] + ws[2] + ws[3];
}

// ---------------- scan stage 2: exclusive scan of NB block sums ----------------
__global__ __launch_bounds__(256) void scan2_kernel(const int* __restrict__ bsum,
                                                    int* __restrict__ ebsum) {
  int tid = threadIdx.x;
  int v = (tid < NB) ? bsum[tid] : 0;
  int ex = block_exscan(v);
  if (tid < NB) ebsum[tid] = ex;
}

// ---------------- scan stage 3: block-local scan + block offset ----------------
__global__ __launch_bounds__(256) void scan3_kernel(const int* __restrict__ cnt,
                                                    const int* __restrict__ ebsum,
                                                    int* __restrict__ offs) {
  int i = blockIdx.x * 256 + threadIdx.x;
  int v = (i < NN) ? cnt[i] : 0;
  int ex = block_exscan(v);
  if (i < NN) offs[i] = ebsum[blockIdx.x] + ex;
}

// ---------------- CSR fill (no atomics: rank precomputed by hist) ----------------
__global__ __launch_bounds__(256) void fill_kernel(const int* __restrict__ row,
                                                   const int* __restrict__ col,
                                                   const int* __restrict__ rank,
                                                   const float* __restrict__ dis,
                                                   const int* __restrict__ offs,
                                                   int2* __restrict__ csr) {
  int e = blockIdx.x * 256 + threadIdx.x;
  if (e < NE) {
    int d = col[e];
    int s = row[e];
    int pos = offs[d] + rank[e];
    csr[pos] = make_int2(s, __float_as_int(dis[s] * dis[d]));
  }
}

// ---------------- split-bf16 MFMA GEMM + fused pointwise epilogue ----------------
// Reordered GCN: gemm consumes agg = A_hat . h (fp16) and applies
// bias + relu + residual(hprev) + LayerNorm, writing h (fp16) + h8 (fp8).
// A-op = W (pre-swizzled, LDS-staged), B-op = X -> lane holds node m0+(lane&15),
// channels t*16 + quad*4 + r (verified layout). Row LN reduction = shfl_xor 16/32
// across the 4 quads sharing a node.
// EMB: input fp32 x, epilogue = bias only. LAST: fused nodeval = h_new . Wout.
template <bool EMB, bool LAST>
__global__ __launch_bounds__(512) void gemm_mfma(const float* __restrict__ Xf,
                                                 const __half* __restrict__ Xh,
                                                 const short* __restrict__ Whi,
                                                 const short* __restrict__ Wlo,
                                                 const float* __restrict__ bias,
                                                 const __half* __restrict__ hprev,
                                                 const float* __restrict__ gamma,
                                                 const float* __restrict__ beta,
                                                 const float* __restrict__ Wout,
                                                 __half* __restrict__ hnew,
                                                 unsigned char* __restrict__ h8,
                                                 float* __restrict__ nodeval) {
  __shared__ short Wh[WSLOT];  // 32 KB
  __shared__ short Wl[WSLOT];  // 32 KB
  int tid = threadIdx.x;
#pragma unroll
  for (int i = tid * 8; i < WSLOT; i += 512 * 8) {
    *(bf16x8*)&Wh[i] = *(const bf16x8*)(Whi + i);
    *(bf16x8*)&Wl[i] = *(const bf16x8*)(Wlo + i);
  }
  __syncthreads();

  int wave = tid >> 6, lane = tid & 63;
  int quad = lane >> 4, r16 = lane & 15;
  int m0 = blockIdx.x * 128 + wave * 16;
  if (m0 >= NN) return;  // NN % 16 == 0
  int mA = m0 + r16;

  f32x4 acc[8];
#pragma unroll
  for (int t = 0; t < 8; ++t) acc[t] = (f32x4){0.f, 0.f, 0.f, 0.f};

#pragma unroll
  for (int ks = 0; ks < 4; ++ks) {
    int klane = ks * 32 + quad * 8;
    float af[8];
    if (EMB) {
      const float* xr = Xf + (size_t)mA * NH + klane;
      float4 a0 = *(const float4*)xr;
      float4 a1 = *(const float4*)(xr + 4);
      af[0] = a0.x; af[1] = a0.y; af[2] = a0.z; af[3] = a0.w;
      af[4] = a1.x; af[5] = a1.y; af[6] = a1.z; af[7] = a1.w;
    } else {
      const __half2* xr = (const __half2*)(Xh + (size_t)mA * NH + klane);
#pragma unroll
      for (int q = 0; q < 4; ++q) {
        float2 f = __half22float2(xr[q]);
        af[2 * q] = f.x;
        af[2 * q + 1] = f.y;
      }
    }
    bf16x8 xhi, xlo;
#pragma unroll
    for (int j = 0; j < 8; ++j) {
      short h = f2bf(af[j]);
      xhi[j] = h;
      xlo[j] = f2bf(af[j] - bf2f(h));
    }
#pragma unroll
    for (int t = 0; t < 8; ++t) {
      int fidx = ((ks * 8 + t) * 64 + lane) << 3;
      bf16x8 whi = *(const bf16x8*)&Wh[fidx];
      bf16x8 wlo = *(const bf16x8*)&Wl[fidx];
      acc[t] = __builtin_amdgcn_mfma_f32_16x16x32_bf16(whi, xhi, acc[t], 0, 0, 0);
      acc[t] = __builtin_amdgcn_mfma_f32_16x16x32_bf16(whi, xlo, acc[t], 0, 0, 0);
      acc[t] = __builtin_amdgcn_mfma_f32_16x16x32_bf16(wlo, xhi, acc[t], 0, 0, 0);
    }
  }

  // ---- epilogue: lane owns node m = m0 + r16, channels ch = t*16 + quad*4 + r
  int m = m0 + r16;
  int cb = quad * 4;  // channel sub-base within the 16-wide tile
  if (EMB) {
#pragma unroll
    for (int t = 0; t < 8; ++t) {
      int ch = t * 16 + cb;
      float4 bb = *(const float4*)(bias + ch);
      float o0 = acc[t][0] + bb.x, o1 = acc[t][1] + bb.y;
      float o2 = acc[t][2] + bb.z, o3 = acc[t][3] + bb.w;
      __half2 p01 = __float22half2_rn(make_float2(o0, o1));
      __half2 p23 = __float22half2_rn(make_float2(o2, o3));
      *(uint2*)(hnew + (size_t)m * NH + ch) =
          make_uint2(*(unsigned*)&p01, *(unsigned*)&p23);
      int v = 0;
      v = __builtin_amdgcn_cvt_pk_fp8_f32(o0, o1, v, 0);
      v = __builtin_amdgcn_cvt_pk_fp8_f32(o2, o3, v, 1);
      ((unsigned*)(h8 + (size_t)m * NH))[t * 4 + quad] = (unsigned)v;
    }
  } else {
    float v[8][4];
    float s = 0.f, s2 = 0.f;
#pragma unroll
    for (int t = 0; t < 8; ++t) {
      int ch = t * 16 + cb;
      float4 bb = *(const float4*)(bias + ch);
      uint2 hp = *(const uint2*)(hprev + (size_t)m * NH + ch);
      float2 h01 = __half22float2(*(__half2*)&hp.x);
      float2 h23 = __half22float2(*(__half2*)&hp.y);
      float hv[4] = {h01.x, h01.y, h23.x, h23.y};
      float bb4[4] = {bb.x, bb.y, bb.z, bb.w};
#pragma unroll
      for (int r = 0; r < 4; ++r) {
        float z = fmaxf(acc[t][r] + bb4[r], 0.f);
        float val = hv[r] + z;
        v[t][r] = val;
        s += val;
        s2 += val * val;
      }
    }
    // reduce across the 4 quads holding this node
    s += __shfl_xor(s, 16, 64);
    s += __shfl_xor(s, 32, 64);
    s2 += __shfl_xor(s2, 16, 64);
    s2 += __shfl_xor(s2, 32, 64);
    float mean = s * (1.f / 128.f);
    float var = fmaxf(s2 * (1.f / 128.f) - mean * mean, 0.f);
    float inv = rsqrtf(var + 1e-5f);
    float d = 0.f;
#pragma unroll
    for (int t = 0; t < 8; ++t) {
      int ch = t * 16 + cb;
      float4 gv = *(const float4*)(gamma + ch);
      float4 bt = *(const float4*)(beta + ch);
      float o0 = (v[t][0] - mean) * inv * gv.x + bt.x;
      float o1 = (v[t][1] - mean) * inv * gv.y + bt.y;
      float o2 = (v[t][2] - mean) * inv * gv.z + bt.z;
      float o3 = (v[t][3] - mean) * inv * gv.w + bt.w;
      __half2 p01 = __float22half2_rn(make_float2(o0, o1));
      __half2 p23 = __float22half2_rn(make_float2(o2, o3));
      *(uint2*)(hnew + (size_t)m * NH + ch) =
          make_uint2(*(unsigned*)&p01, *(unsigned*)&p23);
      if (!LAST) {
        int pv = 0;
        pv = __builtin_amdgcn_cvt_pk_fp8_f32(o0, o1, pv, 0);
        pv = __builtin_amdgcn_cvt_pk_fp8_f32(o2, o3, pv, 1);
        ((unsigned*)(h8 + (size_t)m * NH))[t * 4 + quad] = (unsigned)pv;
      } else {
        float4 wv = *(const float4*)(Wout + ch);
        d += o0 * wv.x + o1 * wv.y + o2 * wv.z + o3 * wv.w;
      }
    }
    if (LAST) {
      d += __shfl_xor(d, 16, 64);
      d += __shfl_xor(d, 32, 64);
      if (lane < 16) nodeval[m] = d;
    }
  }
}

// ---------------- pure gather aggregate: agg = A_hat . h  (fp8 in, fp16 out) ----
// one wave per node; 4 channels/lane x 32 lanes per edge, 2 edges per
// wave-instruction; no epilogue -> minimal VGPRs, max occupancy.
__global__ __launch_bounds__(256) void aggregate_kernel(
    const unsigned char* __restrict__ h8, __half* __restrict__ agg,
    const float* __restrict__ dis, const int* __restrict__ offs,
    const int* __restrict__ cnt, const int2* __restrict__ csr) {
  int node = blockIdx.x * 4 + (threadIdx.x >> 6);
  int lane = threadIdx.x & 63;
  if (node >= NN) return;
  int hf = lane >> 5;        // which edge of the pair
  int c32 = lane & 31;       // dword index within row (4 fp8 channels)
  const unsigned* t32 = (const unsigned*)h8;
  float dii = dis[node];
  float sl = dii * dii;      // self-loop norm
  float4 a = make_float4(0.f, 0.f, 0.f, 0.f);
  if (hf == 0) {  // self loop handled by half 0
    unsigned raw = t32[(size_t)node * 32 + c32];
    f32x2 lo2 = __builtin_amdgcn_cvt_pk_f32_fp8(raw, 0);
    f32x2 hi2 = __builtin_amdgcn_cvt_pk_f32_fp8(raw, 1);
    a.x = lo2.x * sl; a.y = lo2.y * sl; a.z = hi2.x * sl; a.w = hi2.y * sl;
  }
  int s0 = offs[node];
  int e = cnt[node];
  int j = 0;
  for (; j + 16 <= e; j += 16) {  // 8 pairs
    int2 p[8];
    unsigned raw[8];
#pragma unroll
    for (int u = 0; u < 8; ++u) p[u] = csr[s0 + j + 2 * u + hf];
#pragma unroll
    for (int u = 0; u < 8; ++u) raw[u] = t32[(size_t)p[u].x * 32 + c32];
#pragma unroll
    for (int u = 0; u < 8; ++u) {
      float w = __int_as_float(p[u].y);
      f32x2 lo2 = __builtin_amdgcn_cvt_pk_f32_fp8(raw[u], 0);
      f32x2 hi2 = __builtin_amdgcn_cvt_pk_f32_fp8(raw[u], 1);
      a.x += lo2.x * w; a.y += lo2.y * w; a.z += hi2.x * w; a.w += hi2.y * w;
    }
  }
  for (; j + 8 <= e; j += 8) {  // 4 pairs
    int2 p[4];
    unsigned raw[4];
#pragma unroll
    for (int u = 0; u < 4; ++u) p[u] = csr[s0 + j + 2 * u + hf];
#pragma unroll
    for (int u = 0; u < 4; ++u) raw[u] = t32[(size_t)p[u].x * 32 + c32];
#pragma unroll
    for (int u = 0; u < 4; ++u) {
      float w = __int_as_float(p[u].y);
      f32x2 lo2 = __builtin_amdgcn_cvt_pk_f32_fp8(raw[u], 0);
      f32x2 hi2 = __builtin_amdgcn_cvt_pk_f32_fp8(raw[u], 1);
      a.x += lo2.x * w; a.y += lo2.y * w; a.z += hi2.x * w; a.w += hi2.y * w;
    }
  }
  for (; j < e; j += 2) {  // masked tail, 1 pair
    int idx = j + hf;
    int2 p = (idx < e) ? csr[s0 + idx] : make_int2(node, 0);
    float w = __int_as_float(p.y);
    unsigned raw = t32[(size_t)p.x * 32 + c32];
    f32x2 lo2 = __builtin_amdgcn_cvt_pk_f32_fp8(raw, 0);
    f32x2 hi2 = __builtin_amdgcn_cvt_pk_f32_fp8(raw, 1);
    a.x += lo2.x * w; a.y += lo2.y * w; a.z += hi2.x * w; a.w += hi2.y * w;
  }
  // combine the two edge-halves: lanes 0-31 <- + lanes 32-63
  a.x += __shfl_down(a.x, 32, 64);
  a.y += __shfl_down(a.y, 32, 64);
  a.z += __shfl_down(a.z, 32, 64);
  a.w += __shfl_down(a.w, 32, 64);
  if (lane < 32) {
    __half2 p01 = __float22half2_rn(make_float2(a.x, a.y));
    __half2 p23 = __float22half2_rn(make_float2(a.z, a.w));
    *(uint2*)(agg + (size_t)node * NH + (c32 << 2)) =
        make_uint2(*(unsigned*)&p01, *(unsigned*)&p23);
  }
}

// ---------------- LDS-binned segment reduction over sorted batch ----------------
__global__ __launch_bounds__(256) void reduce_pool_kernel(
    const float* __restrict__ nodeval, const int* __restrict__ batch,
    float* __restrict__ gsum, int* __restrict__ gcnt) {
  __shared__ float bins[NG];
  __shared__ int cbins[NG];
  int tid = threadIdx.x;
  if (tid < NG) {
    bins[tid] = 0.f;
    cbins[tid] = 0;
  }
  __syncthreads();
  int i = blockIdx.x * 256 + tid;
  if (i < NN) {
    int g = batch[i];
    atomicAdd(&bins[g], nodeval[i]);
    atomicAdd(&cbins[g], 1);
  }
  __syncthreads();
  if (tid < NG) {
    if (cbins[tid]) {
      atomicAdd(&gsum[tid], bins[tid]);
      atomicAdd(&gcnt[tid], cbins[tid]);
    }
  }
}

__global__ void finalize_kernel(const float* __restrict__ gsum,
                                const int* __restrict__ gcnt,
                                float* __restrict__ out) {
  int g = threadIdx.x;
  if (g < NG) out[g] = gsum[g] / fmaxf((float)gcnt[g], 1.0f);
}

extern "C" void kernel_launch(void* const* d_in, const int* in_sizes, int n_in,
                              void* d_out, int out_size, void* d_ws, size_t ws_size,
                              hipStream_t stream) {
  const float* x = (const float*)d_in[0];
  const int* eidx = (const int*)d_in[1];
  const int* batch = (const int*)d_in[2];
  const float* W_emb = (const float*)d_in[3];
  const float* b_emb = (const float*)d_in[4];
  const float* W_layers = (const float*)d_in[5];
  const float* b_layers = (const float*)d_in[6];
  const float* ln_gamma = (const float*)d_in[7];
  const float* ln_beta = (const float*)d_in[8];
  const float* W_out = (const float*)d_in[9];
  float* out = (float*)d_out;

  char* ws = (char*)d_ws;
  unsigned char* h8 = (unsigned char*)ws; ws += (size_t)NN * NH;  // fp8 trunk
  __half* h = (__half*)ws;      ws += (size_t)NN * NH * 2;        // fp16 trunk
  __half* agg = (__half*)ws;    ws += (size_t)NN * NH * 2;        // fp16 agg
  short* Whi = (short*)ws;      ws += (size_t)5 * WSLOT * 2;
  short* Wlo = (short*)ws;      ws += (size_t)5 * WSLOT * 2;
  float* dis = (float*)ws;      ws += (size_t)NN * 4;
  int2* csr = (int2*)ws;        ws += (size_t)NE * 8;
  int* rank = (int*)ws;         ws += (size_t)NE * 4;
  int* offs = (int*)ws;         ws += (size_t)NN * 4;
  float* nodeval = (float*)ws;  ws += (size_t)NN * 4;
  int* bsum = (int*)ws;         ws += (size_t)NB * 4;
  int* ebsum = (int*)ws;        ws += (size_t)NB * 4;
  char* zero_base = ws;
  int* cnt = (int*)ws;          ws += (size_t)NN * 4;
  float* gsum = (float*)ws;     ws += (size_t)NG * 4;
  int* gcnt = (int*)ws;         ws += (size_t)NG * 4;
  size_t zero_bytes = (size_t)(ws - zero_base);
  hipMemsetAsync(zero_base, 0, zero_bytes, stream);

  const int* erow = eidx;        // edge_index[0] = sources
  const int* ecol = eidx + NE;   // edge_index[1] = targets

  prep_swizzle<<<(5 * WSLOT + 255) / 256, 256, 0, stream>>>(W_emb, W_layers, Whi,
                                                            Wlo);
  hist_kernel<<<(NE + 255) / 256, 256, 0, stream>>>(ecol, cnt, rank);
  scan1_kernel<<<NB, 256, 0, stream>>>(cnt, bsum, dis);
  scan2_kernel<<<1, 256, 0, stream>>>(bsum, ebsum);
  scan3_kernel<<<NB, 256, 0, stream>>>(cnt, ebsum, offs);
  fill_kernel<<<(NE + 255) / 256, 256, 0, stream>>>(erow, ecol, rank, dis, offs,
                                                    csr);
  int gblk = (NN + 127) / 128;
  // embedding: h0 = x @ W_emb^T + b_emb  -> h (fp16) + h8 (fp8)
  gemm_mfma<true, false><<<gblk, 512, 0, stream>>>(
      x, nullptr, Whi, Wlo, b_emb, nullptr, nullptr, nullptr, nullptr, h, h8,
      nullptr);
  for (int l = 0; l < NL; ++l) {
    // agg = A_hat . h  (gather on fp8 trunk)
    aggregate_kernel<<<(NN + 3) / 4, 256, 0, stream>>>(h8, agg, dis, offs, cnt,
                                                       csr);
    // h = LN(h + relu(agg @ W^T + b)); last layer also emits nodeval
    const short* wh = Whi + (size_t)(l + 1) * WSLOT;
    const short* wl = Wlo + (size_t)(l + 1) * WSLOT;
    const float* bl = b_layers + (size_t)l * NH;
    const float* gl = ln_gamma + (size_t)l * NH;
    const float* be = ln_beta + (size_t)l * NH;
    if (l == NL - 1)
      gemm_mfma<false, true><<<gblk, 512, 0, stream>>>(
          nullptr, agg, wh, wl, bl, h, gl, be, W_out, h, h8, nodeval);
    else
      gemm_mfma<false, false><<<gblk, 512, 0, stream>>>(
          nullptr, agg, wh, wl, bl, h, gl, be, nullptr, h, h8, nullptr);
  }
  reduce_pool_kernel<<<(NN + 255) / 256, 256, 0, stream>>>(nodeval, batch, gsum,
                                                           gcnt);
  finalize_kernel<<<1, 64, 0, stream>>>(gsum, gcnt, out);
}